// Round 19
// baseline (864.078 us; speedup 1.0000x reference)
//
#include <hip/hip_runtime.h>
#include <math.h>

constexpr int D_   = 512;   // d_model
constexpr int H_   = 128;   // extractor hidden
constexpr int P_   = 10;    // n_programs
constexpr int MAXO = 4;
constexpr int BM   = 128;   // token tile
constexpr int BK   = 32;    // K chunk (= one MFMA K step)

typedef _Float16 f16;
typedef f16 f16x4 __attribute__((ext_vector_type(4)));
typedef f16 f16x8 __attribute__((ext_vector_type(8)));
typedef float f32x4 __attribute__((ext_vector_type(4)));

__device__ __forceinline__ float gelu_exact(float x) {
    return 0.5f * x * (1.0f + erff(x * 0.70710678118654752f));
}

__device__ __forceinline__ void time_decomp(float t, float& hr, float& mi, float& dy) {
    float days = floorf(t / 1440.0f);
    float rem  = t - days * 1440.0f;
    float hours = floorf(rem / 60.0f);
    float minutes = rem - hours * 60.0f;
    hr = hours; mi = minutes; dy = days;
}

__device__ __forceinline__ void g2l16(const f16* g, f16* l) {
    __builtin_amdgcn_global_load_lds(
        (const __attribute__((address_space(1))) void*)g,
        (__attribute__((address_space(3))) void*)l, 16, 0, 0);
}

// W1 [P][D][H] f32 -> W1T_hi / W1T_lo [P][H][D] f16 (transposed + split; linear,
// consumed by the g2l B-staging path)
__global__ __launch_bounds__(256) void cvt_w1_kernel(
    const float* __restrict__ W1, f16* __restrict__ hi, f16* __restrict__ lo)
{
    int i = blockIdx.x * 256 + threadIdx.x;
    float x = W1[i];
    f16 h = (f16)x;
    f16 L = (f16)(x - (float)h);
    int dh = i % (D_ * H_);
    int p  = i / (D_ * H_);
    int d  = dh / H_;
    int hh = dh % H_;
    size_t o = ((size_t)(p * H_ + hh)) * D_ + d;
    hi[o] = h; lo[o] = L;
}

// Fused: router logits + pids-as-float + hidden -> FRAGMENT-PACKED f16 hi/lo.
// A-fragment (16x16x32): hidF[t16][kc(16)][lane(64)][8];
// lane = l4*16 + row15, holds token t16*16+row15, k = kc*32 + l4*8 + j.
// Split-write vectorized: lane owns k = lane*8..lane*8+7 -> kc=lane>>2,
// l4=lane&3, j contiguous -> one f16x8 store per array.
template <bool WRITE_SPLIT>
__global__ __launch_bounds__(256) void router_cvt_kernel(
    const float* __restrict__ hidden, const float* __restrict__ Wr,
    const float* __restrict__ br, const int* __restrict__ pids,
    float* __restrict__ out_router, float* __restrict__ out_pids,
    f16* __restrict__ hidFhi, f16* __restrict__ hidFlo, int B)
{
    __shared__ float Wrs[D_ * 12];
    const int tid = threadIdx.x;
    for (int i = tid; i < D_ * P_; i += 256) {
        int k = i / P_;
        int q = i - k * P_;
        Wrs[k * 12 + q] = Wr[i];
    }
    __syncthreads();

    const int lane = tid & 63;
    const int wv   = tid >> 6;
    const int b    = blockIdx.x * 4 + wv;
    const float* hrow = hidden + (size_t)b * D_;
    const size_t t16  = (size_t)(b >> 4);
    const int    r15  = b & 15;

    float acc[P_];
#pragma unroll
    for (int q = 0; q < P_; ++q) acc[q] = 0.0f;

#pragma unroll
    for (int j = 0; j < 8; ++j) {
        int k = j * 64 + lane;
        float hv = hrow[k];
        float wv12[12];
        *reinterpret_cast<float4*>(&wv12[0]) = *reinterpret_cast<const float4*>(&Wrs[k * 12 + 0]);
        *reinterpret_cast<float4*>(&wv12[4]) = *reinterpret_cast<const float4*>(&Wrs[k * 12 + 4]);
        *reinterpret_cast<float2*>(&wv12[8]) = *reinterpret_cast<const float2*>(&Wrs[k * 12 + 8]);
#pragma unroll
        for (int q = 0; q < P_; ++q) acc[q] = fmaf(hv, wv12[q], acc[q]);
    }

    if (WRITE_SPLIT) {
        const float* rp = hrow + lane * 8;          // L1-hot re-read
        f32x4 x0 = *(const f32x4*)rp;
        f32x4 x1 = *(const f32x4*)(rp + 4);
        f16x8 hh, ll;
#pragma unroll
        for (int j = 0; j < 4; ++j) {
            f16 h0 = (f16)x0[j]; hh[j] = h0; ll[j] = (f16)(x0[j] - (float)h0);
            f16 h1 = (f16)x1[j]; hh[j + 4] = h1; ll[j + 4] = (f16)(x1[j] - (float)h1);
        }
        size_t off = ((t16 * 16 + (size_t)(lane >> 2)) * 64 + (lane & 3) * 16 + r15) * 8;
        *(f16x8*)(hidFhi + off) = hh;
        *(f16x8*)(hidFlo + off) = ll;
    }

#pragma unroll
    for (int off = 1; off < 64; off <<= 1) {
#pragma unroll
        for (int q = 0; q < P_; ++q)
            acc[q] += __shfl_xor(acc[q], off, 64);
    }

    if (lane == 0) {
        float* o = out_router + (size_t)b * P_;
#pragma unroll
        for (int q = 0; q < P_; ++q) o[q] = acc[q] + br[q];
        out_pids[b] = (float)pids[b];
    }
}

template <bool PRECONV>
__global__ __launch_bounds__(512, 2) void extractor_kernel(
    const float* __restrict__ hidden,   // [B, D] f32 (fallback)
    const f16*   __restrict__ hidFhi,   // packed [t16][kc][64][8] (PRECONV)
    const f16*   __restrict__ hidFlo,
    const int*   __restrict__ pids,     // [B]
    const f16*   __restrict__ W1Thi,    // [P][H][D] linear
    const f16*   __restrict__ W1Tlo,    // [P][H][D] linear
    const float* __restrict__ b1,       // [P, H]
    const float* __restrict__ W2,       // [P, H, MAXO]
    const float* __restrict__ b2,       // [P, MAXO]
    float* __restrict__ out_results,    // [B, 3]
    float* __restrict__ out_ops,        // [P, B, MAXO]
    int B)
{
    // LDS: B-staging 4-deep {Bh 8K | Bl 8K} x4 = 64K | red 4K | W2s 2K = 71680.
    // 4-deep + single barrier/chunk: WAR distance stage(k+2..k+3) vs
    // compute(k) is >=3 mod 4 even with 1-iteration wave skew.
    __shared__ __align__(16) char smem[71680];
    float* red = (float*)(smem + 65536);   // [2][128][4]
    float* W2s = (float*)(smem + 69632);   // [128][4]

    const int bid = blockIdx.x;
    const int ngroups = gridDim.x / P_;
    int g, p;
    if ((ngroups & 7) == 0) {
        // XCD-aware: hw xcd = bid % 8; each XCD gets contiguous (tile, program)
        // groups so a tile's 10 program-blocks share one L2.
        const int gpx = ngroups >> 3;
        const int x   = bid & 7;
        const int q   = bid >> 3;
        g = x * gpx + q / P_;
        p = q % P_;
    } else {
        g = bid / P_;
        p = bid % P_;
    }
    const int b0  = g * BM;
    const int tid = threadIdx.x;
    const int l   = tid & 63;
    const int w   = tid >> 6;          // 8 waves
    const int wm  = w >> 1, wn = w & 1; // wave tile: 32 tok x 64 h
    const int l15 = l & 15, l4 = l >> 4;

    // ---- B swizzle (both-sides involution; proven 0-conflict) ----
    const int sg8 = (((l & 3) ^ ((l >> 3) & 3))) * 8;     // stage-side, f16 units
    const int rd8 = ((l4 ^ ((l15 >> 1) & 3))) * 8;        // read-side, f16 units

    if (tid < H_) {
        ((f32x4*)W2s)[tid] = ((const f32x4*)(W2 + (size_t)p * H_ * 4))[tid];
    }

    f32x4 acc[2][4];
#pragma unroll
    for (int mi = 0; mi < 2; ++mi)
#pragma unroll
        for (int ni = 0; ni < 4; ++ni) acc[mi][ni] = (f32x4){0.f, 0.f, 0.f, 0.f};

    const f16* Bhig = W1Thi + (size_t)p * H_ * D_;
    const f16* Blog = W1Tlo + (size_t)p * H_ * D_;

    // B staging: 2 g2l per wave (16-row unit); buffer offset computed inline
    auto stageB = [&](int kc, int bi) {
        f16* Bh = (f16*)(smem + bi * 16384);
        f16* Bl = (f16*)(smem + bi * 16384 + 8192);
        const int r0 = w * 16;
        size_t gb = (size_t)(r0 + (l >> 2)) * D_ + kc * BK + sg8;
        g2l16(Bhig + gb, Bh + r0 * BK);
        g2l16(Blog + gb, Bl + r0 * BK);
    };

    // A: direct global->VGPR, fragment-packed contiguous 1KB loads (PRECONV)
    auto loadA = [&](int kc, f16x8* aH, f16x8* aL) {
        if constexpr (PRECONV) {
#pragma unroll
            for (int mi = 0; mi < 2; ++mi) {
                const size_t off =
                    (((size_t)(b0 / 16 + wm * 2 + mi) * 16 + kc) * 64 + l) * 8;
                aH[mi] = *(const f16x8*)(hidFhi + off);
                aL[mi] = *(const f16x8*)(hidFlo + off);
            }
        }
    };

    auto compute = [&](int bi, const f16x8* aH, const f16x8* aL, int kc) {
        const f16* Bh = (const f16*)(smem + bi * 16384);
        const f16* Bl = (const f16*)(smem + bi * 16384 + 8192);
        f16x8 bh[4], bl[4];
#pragma unroll
        for (int ni = 0; ni < 4; ++ni) {
            int hrow = wn * 64 + ni * 16 + l15;
            bh[ni] = *(const f16x8*)&Bh[hrow * BK + rd8];
            bl[ni] = *(const f16x8*)&Bl[hrow * BK + rd8];
        }
#pragma unroll
        for (int mi = 0; mi < 2; ++mi) {
            f16x8 a_h, a_l;
            if constexpr (PRECONV) {
                a_h = aH[mi]; a_l = aL[mi];
            } else {
                const float* rp = hidden + (size_t)(b0 + wm * 32 + mi * 16 + l15) * D_
                                 + kc * BK + l4 * 8;
                f32x4 x0 = *(const f32x4*)rp;
                f32x4 x1 = *(const f32x4*)(rp + 4);
#pragma unroll
                for (int j = 0; j < 4; ++j) {
                    f16 h0 = (f16)x0[j]; a_h[j] = h0; a_l[j] = (f16)(x0[j] - (float)h0);
                    f16 h1 = (f16)x1[j]; a_h[j + 4] = h1; a_l[j + 4] = (f16)(x1[j] - (float)h1);
                }
            }
            // T5: boost wave priority through the MFMA cluster (valid now that
            // the single-barrier schedule de-syncs wave roles within a chunk)
            __builtin_amdgcn_s_setprio(1);
#pragma unroll
            for (int ni = 0; ni < 4; ++ni) {
                acc[mi][ni] = __builtin_amdgcn_mfma_f32_16x16x32_f16(a_l, bh[ni], acc[mi][ni], 0, 0, 0);
                acc[mi][ni] = __builtin_amdgcn_mfma_f32_16x16x32_f16(a_h, bl[ni], acc[mi][ni], 0, 0, 0);
                acc[mi][ni] = __builtin_amdgcn_mfma_f32_16x16x32_f16(a_h, bh[ni], acc[mi][ni], 0, 0, 0);
            }
            __builtin_amdgcn_s_setprio(0);
        }
    };

    f16x8 aHa[2], aLa[2], aHb[2], aLb[2];

    if constexpr (PRECONV) {
        // 4-deep B pipeline, 2-deep A regs, ONE barrier per chunk.
        // vmcnt(6) steady = {A(k+1)x4, B(k+2)x2} stay in flight (T4: never 0
        // until the tail). Queue audit at barrier(k): [A(k)4,B(k+1)2,A(k+1)4,
        // B(k+2)2]=12 -> drain 6 = A(k)+B(k+1); B(k) drained earlier.
        stageB(0, 0);
        stageB(1, 1);
        loadA(0, aHa, aLa);
#pragma unroll
        for (int kc = 0; kc < 16; ++kc) {
            if (kc + 1 < 16) {
                if (kc & 1) loadA(kc + 1, aHa, aLa);
                else        loadA(kc + 1, aHb, aLb);
            }
            if (kc + 2 < 16) stageB(kc + 2, (kc + 2) & 3);
            if (kc <= 14) asm volatile("s_waitcnt vmcnt(6)" ::: "memory");
            else          asm volatile("s_waitcnt vmcnt(0)" ::: "memory");
            __builtin_amdgcn_s_barrier();
            if (kc & 1) compute(kc & 3, aHb, aLb, kc);
            else        compute(kc & 3, aHa, aLa, kc);
        }
    } else {
        // simple correct fallback: B dbuf via syncthreads; A from f32 inline
        stageB(0, 0);
        __syncthreads();
        for (int kc = 0; kc < 16; ++kc) {
            if (kc < 15) stageB(kc + 1, (kc + 1) & 1);
            compute(kc & 1, aHa, aLa, kc);
            __syncthreads();
        }
    }

    // ---- epilogue: bias + exact gelu + GEMM2 via 16-lane butterfly ----
    float b1v[4];
#pragma unroll
    for (int ni = 0; ni < 4; ++ni)
        b1v[ni] = b1[p * H_ + wn * 64 + ni * 16 + l15];

#pragma unroll
    for (int mi = 0; mi < 2; ++mi) {
        float po[4][4];
#pragma unroll
        for (int r = 0; r < 4; ++r)
#pragma unroll
            for (int o = 0; o < 4; ++o) po[r][o] = 0.0f;

#pragma unroll
        for (int ni = 0; ni < 4; ++ni) {
            int h = wn * 64 + ni * 16 + l15;
            f32x4 w4 = ((const f32x4*)W2s)[h];
#pragma unroll
            for (int r = 0; r < 4; ++r) {
                float gg = gelu_exact(acc[mi][ni][r] + b1v[ni]);
#pragma unroll
                for (int o = 0; o < 4; ++o) po[r][o] = fmaf(gg, w4[o], po[r][o]);
            }
        }
#pragma unroll
        for (int off = 1; off < 16; off <<= 1) {
#pragma unroll
            for (int r = 0; r < 4; ++r)
#pragma unroll
                for (int o = 0; o < 4; ++o)
                    po[r][o] += __shfl_xor(po[r][o], off, 64);
        }
        float v = po[0][0];
#pragma unroll
        for (int rr = 0; rr < 4; ++rr)
#pragma unroll
            for (int oo = 0; oo < 4; ++oo)
                if (l15 == rr * 4 + oo) v = po[rr][oo];
        red[(wn * 128 + wm * 32 + mi * 16 + l4 * 4 + (l15 >> 2)) * 4 + (l15 & 3)] = v;
    }
    __syncthreads();

    if (tid < BM) {
        int b = b0 + tid;
        const float* r0p = &red[(0 * 128 + tid) * 4];
        const float* r1p = &red[(1 * 128 + tid) * 4];
        float o0 = r0p[0] + r1p[0] + b2[p * 4 + 0];
        float o1 = r0p[1] + r1p[1] + b2[p * 4 + 1];
        float o2 = r0p[2] + r1p[2] + b2[p * 4 + 2];
        float o3 = r0p[3] + r1p[3] + b2[p * 4 + 3];
        *reinterpret_cast<float4*>(out_ops + ((size_t)p * B + b) * MAXO) =
            make_float4(o0, o1, o2, o3);

        if (pids[b] == p) {
            float a0 = rintf(o0), a1 = rintf(o1), a2 = rintf(o2), a3 = rintf(o3);
            float r0 = 0.0f, r1 = 0.0f, r2 = 0.0f;
            switch (p) {
                case 0: r0 = a0 + a1; break;
                case 1: r0 = a0 - a1; break;
                case 2: r0 = a0 * a1; break;
                case 3: {
                    float bs = (a1 == 0.0f) ? 1.0f : a1;
                    float m = fmodf(a0, bs);
                    if (m != 0.0f && ((m < 0.0f) != (bs < 0.0f))) m += bs;
                    r0 = m;
                } break;
                case 4: {
                    float bs = (a1 == 0.0f) ? 1.0f : a1;
                    r0 = floorf(a0 / bs);
                } break;
                case 5: { float tt = a0 * 60.0f + a1 + a2 * 60.0f + a3; time_decomp(tt, r0, r1, r2); } break;
                case 6: { float tt = a0 * 60.0f + a1 - (a2 * 60.0f + a3); time_decomp(tt, r0, r1, r2); } break;
                case 7: { float tt = fabsf(a0 * 60.0f + a1 - (a2 * 60.0f + a3)); time_decomp(tt, r0, r1, r2); } break;
                case 8: r0 = (a0 > a1) ? 1.0f : 0.0f; break;
                case 9: r0 = (a0 == a1) ? 1.0f : 0.0f; break;
            }
            size_t ob = (size_t)b * 3;
            out_results[ob + 0] = r0;
            out_results[ob + 1] = r1;
            out_results[ob + 2] = r2;
        }
    }
}

extern "C" void kernel_launch(void* const* d_in, const int* in_sizes, int n_in,
                              void* d_out, int out_size, void* d_ws, size_t ws_size,
                              hipStream_t stream) {
    const float* hidden = (const float*)d_in[0];
    const int*   pids   = (const int*)  d_in[1];
    const float* Wr     = (const float*)d_in[2];
    const float* br     = (const float*)d_in[3];
    const float* W1     = (const float*)d_in[4];
    const float* b1     = (const float*)d_in[5];
    const float* W2     = (const float*)d_in[6];
    const float* b2     = (const float*)d_in[7];

    const int B = in_sizes[1];

    float* out         = (float*)d_out;
    float* out_results = out;                                          // [B,3]
    float* out_router  = out + (size_t)B * 3;                          // [B,10]
    float* out_ops     = out + (size_t)B * 13;                         // [P,B,4]
    float* out_pids    = out + (size_t)B * 13 + (size_t)P_ * B * MAXO; // [B]

    const size_t nW1  = (size_t)P_ * H_ * D_;
    const size_t nHid = (size_t)B * D_;
    const size_t need = (2 * nW1 + 2 * nHid) * sizeof(f16);

    f16* W1Thi = (f16*)d_ws;
    f16* W1Tlo = W1Thi + nW1;

    cvt_w1_kernel<<<(int)(nW1 / 256), 256, 0, stream>>>(W1, W1Thi, W1Tlo);

    if (ws_size >= need) {
        f16* hidFhi = W1Tlo + nW1;
        f16* hidFlo = hidFhi + nHid;
        router_cvt_kernel<true><<<B / 4, 256, 0, stream>>>(
            hidden, Wr, br, pids, out_router, out_pids, hidFhi, hidFlo, B);
        extractor_kernel<true><<<(B / BM) * P_, 512, 0, stream>>>(
            hidden, hidFhi, hidFlo, pids, W1Thi, W1Tlo, b1, W2, b2,
            out_results, out_ops, B);
    } else {
        router_cvt_kernel<false><<<B / 4, 256, 0, stream>>>(
            hidden, Wr, br, pids, out_router, out_pids, nullptr, nullptr, B);
        extractor_kernel<false><<<(B / BM) * P_, 512, 0, stream>>>(
            hidden, nullptr, nullptr, pids, W1Thi, W1Tlo, b1, W2, b2,
            out_results, out_ops, B);
    }
}

// Round 20
// 748.830 us; speedup vs baseline: 1.1539x; 1.1539x over previous
//
#include <hip/hip_runtime.h>
#include <math.h>

constexpr int D_   = 512;   // d_model
constexpr int H_   = 128;   // extractor hidden
constexpr int P_   = 10;    // n_programs
constexpr int MAXO = 4;
constexpr int BM   = 128;   // token tile
constexpr int BK   = 32;    // K chunk (= one MFMA K step)

typedef _Float16 f16;
typedef f16 f16x4 __attribute__((ext_vector_type(4)));
typedef f16 f16x8 __attribute__((ext_vector_type(8)));
typedef float f32x4 __attribute__((ext_vector_type(4)));

__device__ __forceinline__ float gelu_exact(float x) {
    return 0.5f * x * (1.0f + erff(x * 0.70710678118654752f));
}

__device__ __forceinline__ void time_decomp(float t, float& hr, float& mi, float& dy) {
    float days = floorf(t / 1440.0f);
    float rem  = t - days * 1440.0f;
    float hours = floorf(rem / 60.0f);
    float minutes = rem - hours * 60.0f;
    hr = hours; mi = minutes; dy = days;
}

__device__ __forceinline__ void g2l16(const f16* g, f16* l) {
    __builtin_amdgcn_global_load_lds(
        (const __attribute__((address_space(1))) void*)g,
        (__attribute__((address_space(3))) void*)l, 16, 0, 0);
}

// Fused: router logits + pids-as-float + hidden split + W1 transpose/split.
// Blocks [0, nW1/256) additionally convert 256 W1 elements each:
//   W1 [P][D][H] f32 -> W1T_hi / W1T_lo [P][H][D] f16.
// hidden -> FRAGMENT-PACKED f16 hi/lo: hidF[t16][kc(16)][lane(64)][8];
// lane = l4*16 + row15 holds token t16*16+row15, k = kc*32 + l4*8 + j.
template <bool WRITE_SPLIT>
__global__ __launch_bounds__(256) void router_cvt_kernel(
    const float* __restrict__ hidden, const float* __restrict__ Wr,
    const float* __restrict__ br, const int* __restrict__ pids,
    const float* __restrict__ W1,
    f16* __restrict__ W1Thi, f16* __restrict__ W1Tlo,
    float* __restrict__ out_router, float* __restrict__ out_pids,
    f16* __restrict__ hidFhi, f16* __restrict__ hidFlo, int B)
{
    __shared__ float Wrs[D_ * 12];
    const int tid = threadIdx.x;

    // fused W1 conversion (first nW1/256 blocks; one element per thread)
    {
        int i = blockIdx.x * 256 + tid;
        if (i < P_ * D_ * H_) {
            float x = W1[i];
            f16 h = (f16)x;
            f16 L = (f16)(x - (float)h);
            int dh = i % (D_ * H_);
            int p  = i / (D_ * H_);
            int d  = dh / H_;
            int hh = dh % H_;
            size_t o = ((size_t)(p * H_ + hh)) * D_ + d;
            W1Thi[o] = h; W1Tlo[o] = L;
        }
    }

    for (int i = tid; i < D_ * P_; i += 256) {
        int k = i / P_;
        int q = i - k * P_;
        Wrs[k * 12 + q] = Wr[i];
    }
    __syncthreads();

    const int lane = tid & 63;
    const int wv   = tid >> 6;
    const int b    = blockIdx.x * 4 + wv;
    const float* hrow = hidden + (size_t)b * D_;
    const size_t t16  = (size_t)(b >> 4);
    const int    r15  = b & 15;

    float acc[P_];
#pragma unroll
    for (int q = 0; q < P_; ++q) acc[q] = 0.0f;

#pragma unroll
    for (int j = 0; j < 8; ++j) {
        int k = j * 64 + lane;
        float hv = hrow[k];
        float wv12[12];
        *reinterpret_cast<float4*>(&wv12[0]) = *reinterpret_cast<const float4*>(&Wrs[k * 12 + 0]);
        *reinterpret_cast<float4*>(&wv12[4]) = *reinterpret_cast<const float4*>(&Wrs[k * 12 + 4]);
        *reinterpret_cast<float2*>(&wv12[8]) = *reinterpret_cast<const float2*>(&Wrs[k * 12 + 8]);
#pragma unroll
        for (int q = 0; q < P_; ++q) acc[q] = fmaf(hv, wv12[q], acc[q]);
    }

    if (WRITE_SPLIT) {
        const float* rp = hrow + lane * 8;          // L1-hot re-read
        f32x4 x0 = *(const f32x4*)rp;
        f32x4 x1 = *(const f32x4*)(rp + 4);
        f16x8 hh, ll;
#pragma unroll
        for (int j = 0; j < 4; ++j) {
            f16 h0 = (f16)x0[j]; hh[j] = h0; ll[j] = (f16)(x0[j] - (float)h0);
            f16 h1 = (f16)x1[j]; hh[j + 4] = h1; ll[j + 4] = (f16)(x1[j] - (float)h1);
        }
        size_t off = ((t16 * 16 + (size_t)(lane >> 2)) * 64 + (lane & 3) * 16 + r15) * 8;
        *(f16x8*)(hidFhi + off) = hh;
        *(f16x8*)(hidFlo + off) = ll;
    }

#pragma unroll
    for (int off = 1; off < 64; off <<= 1) {
#pragma unroll
        for (int q = 0; q < P_; ++q)
            acc[q] += __shfl_xor(acc[q], off, 64);
    }

    if (lane == 0) {
        float* o = out_router + (size_t)b * P_;
#pragma unroll
        for (int q = 0; q < P_; ++q) o[q] = acc[q] + br[q];
        out_pids[b] = (float)pids[b];
    }
}

template <bool PRECONV>
__global__ __launch_bounds__(512, 2) void extractor_kernel(
    const float* __restrict__ hidden,   // [B, D] f32 (fallback)
    const f16*   __restrict__ hidFhi,   // packed [t16][kc][64][8] (PRECONV)
    const f16*   __restrict__ hidFlo,
    const int*   __restrict__ pids,     // [B]
    const f16*   __restrict__ W1Thi,    // [P][H][D] linear
    const f16*   __restrict__ W1Tlo,    // [P][H][D] linear
    const float* __restrict__ b1,       // [P, H]
    const float* __restrict__ W2,       // [P, H, MAXO]
    const float* __restrict__ b2,       // [P, MAXO]
    float* __restrict__ out_results,    // [B, 3]
    float* __restrict__ out_ops,        // [P, B, MAXO]
    int B)
{
    // LDS: B-staging 4-deep {Bh 8K | Bl 8K} x4 = 64K | red 4K | W2s 2K = 71680.
    // 4-deep + single barrier/chunk: WAR distance stage(k+2..k+3) vs
    // compute(k) is >=3 mod 4 even with 1-iteration wave skew.
    __shared__ __align__(16) char smem[71680];
    float* red = (float*)(smem + 65536);   // [2][128][4]
    float* W2s = (float*)(smem + 69632);   // [128][4]

    const int bid = blockIdx.x;
    const int ngroups = gridDim.x / P_;
    int g, p;
    if ((ngroups & 7) == 0) {
        // XCD-aware: hw xcd = bid % 8; each XCD gets contiguous (tile, program)
        // groups so a tile's 10 program-blocks share one L2.
        const int gpx = ngroups >> 3;
        const int x   = bid & 7;
        const int q   = bid >> 3;
        g = x * gpx + q / P_;
        p = q % P_;
    } else {
        g = bid / P_;
        p = bid % P_;
    }
    const int b0  = g * BM;
    const int tid = threadIdx.x;
    const int l   = tid & 63;
    const int w   = tid >> 6;          // 8 waves
    const int wm  = w >> 1, wn = w & 1; // wave tile: 32 tok x 64 h
    const int l15 = l & 15, l4 = l >> 4;

    // ---- B swizzle (both-sides involution; proven 0-conflict) ----
    const int sg8 = (((l & 3) ^ ((l >> 3) & 3))) * 8;     // stage-side, f16 units
    const int rd8 = ((l4 ^ ((l15 >> 1) & 3))) * 8;        // read-side, f16 units

    if (tid < H_) {
        ((f32x4*)W2s)[tid] = ((const f32x4*)(W2 + (size_t)p * H_ * 4))[tid];
    }

    f32x4 acc[2][4];
#pragma unroll
    for (int mi = 0; mi < 2; ++mi)
#pragma unroll
        for (int ni = 0; ni < 4; ++ni) acc[mi][ni] = (f32x4){0.f, 0.f, 0.f, 0.f};

    const f16* Bhig = W1Thi + (size_t)p * H_ * D_;
    const f16* Blog = W1Tlo + (size_t)p * H_ * D_;

    // B staging: 2 g2l per wave (16-row unit); buffer offset computed inline
    auto stageB = [&](int kc, int bi) {
        f16* Bh = (f16*)(smem + bi * 16384);
        f16* Bl = (f16*)(smem + bi * 16384 + 8192);
        const int r0 = w * 16;
        size_t gb = (size_t)(r0 + (l >> 2)) * D_ + kc * BK + sg8;
        g2l16(Bhig + gb, Bh + r0 * BK);
        g2l16(Blog + gb, Bl + r0 * BK);
    };

    // A: direct global->VGPR, fragment-packed contiguous 1KB loads (PRECONV)
    auto loadA = [&](int kc, f16x8* aH, f16x8* aL) {
        if constexpr (PRECONV) {
#pragma unroll
            for (int mi = 0; mi < 2; ++mi) {
                const size_t off =
                    (((size_t)(b0 / 16 + wm * 2 + mi) * 16 + kc) * 64 + l) * 8;
                aH[mi] = *(const f16x8*)(hidFhi + off);
                aL[mi] = *(const f16x8*)(hidFlo + off);
            }
        }
    };

    auto compute = [&](int bi, const f16x8* aH, const f16x8* aL, int kc) {
        const f16* Bh = (const f16*)(smem + bi * 16384);
        const f16* Bl = (const f16*)(smem + bi * 16384 + 8192);
        f16x8 bh[4], bl[4];
#pragma unroll
        for (int ni = 0; ni < 4; ++ni) {
            int hrow = wn * 64 + ni * 16 + l15;
            bh[ni] = *(const f16x8*)&Bh[hrow * BK + rd8];
            bl[ni] = *(const f16x8*)&Bl[hrow * BK + rd8];
        }
#pragma unroll
        for (int mi = 0; mi < 2; ++mi) {
            f16x8 a_h, a_l;
            if constexpr (PRECONV) {
                a_h = aH[mi]; a_l = aL[mi];
            } else {
                const float* rp = hidden + (size_t)(b0 + wm * 32 + mi * 16 + l15) * D_
                                 + kc * BK + l4 * 8;
                f32x4 x0 = *(const f32x4*)rp;
                f32x4 x1 = *(const f32x4*)(rp + 4);
#pragma unroll
                for (int j = 0; j < 4; ++j) {
                    f16 h0 = (f16)x0[j]; a_h[j] = h0; a_l[j] = (f16)(x0[j] - (float)h0);
                    f16 h1 = (f16)x1[j]; a_h[j + 4] = h1; a_l[j + 4] = (f16)(x1[j] - (float)h1);
                }
            }
#pragma unroll
            for (int ni = 0; ni < 4; ++ni) {
                acc[mi][ni] = __builtin_amdgcn_mfma_f32_16x16x32_f16(a_l, bh[ni], acc[mi][ni], 0, 0, 0);
                acc[mi][ni] = __builtin_amdgcn_mfma_f32_16x16x32_f16(a_h, bl[ni], acc[mi][ni], 0, 0, 0);
                acc[mi][ni] = __builtin_amdgcn_mfma_f32_16x16x32_f16(a_h, bh[ni], acc[mi][ni], 0, 0, 0);
            }
        }
    };

    f16x8 aHa[2], aLa[2], aHb[2], aLb[2];

    if constexpr (PRECONV) {
        // 4-deep B pipeline, 2-deep A regs, ONE barrier per chunk.
        // vmcnt(6) steady = {A(k+1)x4, B(k+2)x2} stay in flight (T4: never 0
        // until the tail). Queue audit at barrier(k): [A(k)4,B(k+1)2,A(k+1)4,
        // B(k+2)2]=12 -> drain 6 = A(k)+B(k+1); B(k) drained earlier.
        stageB(0, 0);
        stageB(1, 1);
        loadA(0, aHa, aLa);
#pragma unroll
        for (int kc = 0; kc < 16; ++kc) {
            if (kc + 1 < 16) {
                if (kc & 1) loadA(kc + 1, aHa, aLa);
                else        loadA(kc + 1, aHb, aLb);
            }
            if (kc + 2 < 16) stageB(kc + 2, (kc + 2) & 3);
            if (kc <= 14) asm volatile("s_waitcnt vmcnt(6)" ::: "memory");
            else          asm volatile("s_waitcnt vmcnt(0)" ::: "memory");
            __builtin_amdgcn_s_barrier();
            if (kc & 1) compute(kc & 3, aHb, aLb, kc);
            else        compute(kc & 3, aHa, aLa, kc);
        }
    } else {
        // simple correct fallback: B dbuf via syncthreads; A from f32 inline
        stageB(0, 0);
        __syncthreads();
        for (int kc = 0; kc < 16; ++kc) {
            if (kc < 15) stageB(kc + 1, (kc + 1) & 1);
            compute(kc & 1, aHa, aLa, kc);
            __syncthreads();
        }
    }

    // ---- epilogue: bias + exact gelu + GEMM2 via 16-lane butterfly ----
    float b1v[4];
#pragma unroll
    for (int ni = 0; ni < 4; ++ni)
        b1v[ni] = b1[p * H_ + wn * 64 + ni * 16 + l15];

#pragma unroll
    for (int mi = 0; mi < 2; ++mi) {
        float po[4][4];
#pragma unroll
        for (int r = 0; r < 4; ++r)
#pragma unroll
            for (int o = 0; o < 4; ++o) po[r][o] = 0.0f;

#pragma unroll
        for (int ni = 0; ni < 4; ++ni) {
            int h = wn * 64 + ni * 16 + l15;
            f32x4 w4 = ((const f32x4*)W2s)[h];
#pragma unroll
            for (int r = 0; r < 4; ++r) {
                float gg = gelu_exact(acc[mi][ni][r] + b1v[ni]);
#pragma unroll
                for (int o = 0; o < 4; ++o) po[r][o] = fmaf(gg, w4[o], po[r][o]);
            }
        }
#pragma unroll
        for (int off = 1; off < 16; off <<= 1) {
#pragma unroll
            for (int r = 0; r < 4; ++r)
#pragma unroll
                for (int o = 0; o < 4; ++o)
                    po[r][o] += __shfl_xor(po[r][o], off, 64);
        }
        float v = po[0][0];
#pragma unroll
        for (int rr = 0; rr < 4; ++rr)
#pragma unroll
            for (int oo = 0; oo < 4; ++oo)
                if (l15 == rr * 4 + oo) v = po[rr][oo];
        red[(wn * 128 + wm * 32 + mi * 16 + l4 * 4 + (l15 >> 2)) * 4 + (l15 & 3)] = v;
    }
    __syncthreads();

    if (tid < BM) {
        int b = b0 + tid;
        const float* r0p = &red[(0 * 128 + tid) * 4];
        const float* r1p = &red[(1 * 128 + tid) * 4];
        float o0 = r0p[0] + r1p[0] + b2[p * 4 + 0];
        float o1 = r0p[1] + r1p[1] + b2[p * 4 + 1];
        float o2 = r0p[2] + r1p[2] + b2[p * 4 + 2];
        float o3 = r0p[3] + r1p[3] + b2[p * 4 + 3];
        *reinterpret_cast<float4*>(out_ops + ((size_t)p * B + b) * MAXO) =
            make_float4(o0, o1, o2, o3);

        if (pids[b] == p) {
            float a0 = rintf(o0), a1 = rintf(o1), a2 = rintf(o2), a3 = rintf(o3);
            float r0 = 0.0f, r1 = 0.0f, r2 = 0.0f;
            switch (p) {
                case 0: r0 = a0 + a1; break;
                case 1: r0 = a0 - a1; break;
                case 2: r0 = a0 * a1; break;
                case 3: {
                    float bs = (a1 == 0.0f) ? 1.0f : a1;
                    float m = fmodf(a0, bs);
                    if (m != 0.0f && ((m < 0.0f) != (bs < 0.0f))) m += bs;
                    r0 = m;
                } break;
                case 4: {
                    float bs = (a1 == 0.0f) ? 1.0f : a1;
                    r0 = floorf(a0 / bs);
                } break;
                case 5: { float tt = a0 * 60.0f + a1 + a2 * 60.0f + a3; time_decomp(tt, r0, r1, r2); } break;
                case 6: { float tt = a0 * 60.0f + a1 - (a2 * 60.0f + a3); time_decomp(tt, r0, r1, r2); } break;
                case 7: { float tt = fabsf(a0 * 60.0f + a1 - (a2 * 60.0f + a3)); time_decomp(tt, r0, r1, r2); } break;
                case 8: r0 = (a0 > a1) ? 1.0f : 0.0f; break;
                case 9: r0 = (a0 == a1) ? 1.0f : 0.0f; break;
            }
            size_t ob = (size_t)b * 3;
            out_results[ob + 0] = r0;
            out_results[ob + 1] = r1;
            out_results[ob + 2] = r2;
        }
    }
}

extern "C" void kernel_launch(void* const* d_in, const int* in_sizes, int n_in,
                              void* d_out, int out_size, void* d_ws, size_t ws_size,
                              hipStream_t stream) {
    const float* hidden = (const float*)d_in[0];
    const int*   pids   = (const int*)  d_in[1];
    const float* Wr     = (const float*)d_in[2];
    const float* br     = (const float*)d_in[3];
    const float* W1     = (const float*)d_in[4];
    const float* b1     = (const float*)d_in[5];
    const float* W2     = (const float*)d_in[6];
    const float* b2     = (const float*)d_in[7];

    const int B = in_sizes[1];

    float* out         = (float*)d_out;
    float* out_results = out;                                          // [B,3]
    float* out_router  = out + (size_t)B * 3;                          // [B,10]
    float* out_ops     = out + (size_t)B * 13;                         // [P,B,4]
    float* out_pids    = out + (size_t)B * 13 + (size_t)P_ * B * MAXO; // [B]

    const size_t nW1  = (size_t)P_ * H_ * D_;
    const size_t nHid = (size_t)B * D_;
    const size_t need = (2 * nW1 + 2 * nHid) * sizeof(f16);

    f16* W1Thi = (f16*)d_ws;
    f16* W1Tlo = W1Thi + nW1;

    if (ws_size >= need) {
        f16* hidFhi = W1Tlo + nW1;
        f16* hidFlo = hidFhi + nHid;
        router_cvt_kernel<true><<<B / 4, 256, 0, stream>>>(
            hidden, Wr, br, pids, W1, W1Thi, W1Tlo,
            out_router, out_pids, hidFhi, hidFlo, B);
        extractor_kernel<true><<<(B / BM) * P_, 512, 0, stream>>>(
            hidden, hidFhi, hidFlo, pids, W1Thi, W1Tlo, b1, W2, b2,
            out_results, out_ops, B);
    } else {
        router_cvt_kernel<false><<<B / 4, 256, 0, stream>>>(
            hidden, Wr, br, pids, W1, W1Thi, W1Tlo,
            out_router, out_pids, nullptr, nullptr, B);
        extractor_kernel<false><<<(B / BM) * P_, 512, 0, stream>>>(
            hidden, nullptr, nullptr, pids, W1Thi, W1Tlo, b1, W2, b2,
            out_results, out_ops, B);
    }
}